// Round 10
// baseline (360.258 us; speedup 1.0000x reference)
//
#include <hip/hip_runtime.h>
#include <math.h>

#define SEQ 577
#define NH 12
#define DH 64
#define EMB 768
#define NBATCH 16
#define NC 2
#define BC (NBATCH/NC)
#define MC (BC*SEQ)      // 4616 rows per chunk
#define BHC (BC*NH)      // 96 (b,h) per chunk
#define VTS 592          // vt row stride in m (16 ushort aligned, >= 577)

typedef float f32x4 __attribute__((ext_vector_type(4)));
typedef short s16x8 __attribute__((ext_vector_type(8)));

__device__ __forceinline__ float bf2f(unsigned short u) {
  union { unsigned int i; float f; } c; c.i = ((unsigned int)u) << 16; return c.f;
}
__device__ __forceinline__ unsigned short f2bf(float f) {
  union { float f; unsigned int i; } c; c.f = f;
  unsigned int r = c.i + 0x7FFFu + ((c.i >> 16) & 1u);   // round-nearest-even
  return (unsigned short)(r >> 16);
}

// Async global->LDS, 16B per lane. LDS dest is wave-uniform base + lane*16.
__device__ __forceinline__ void gl_lds16(const unsigned short* g, unsigned short* l) {
  __builtin_amdgcn_global_load_lds(
      (const __attribute__((address_space(1))) unsigned int*)g,
      (__attribute__((address_space(3))) unsigned int*)l, 16, 0, 0);
}

// ---------------------------------------------------------------------------
__global__ __launch_bounds__(256) void cast_kernel(
    const float* __restrict__ s, unsigned short* __restrict__ d, int n4)
{
  int i = blockIdx.x * 256 + threadIdx.x;
  if (i < n4) {
    float4 v = *(const float4*)&s[(size_t)i*4];
    ushort4 o; o.x = f2bf(v.x); o.y = f2bf(v.y); o.z = f2bf(v.z); o.w = f2bf(v.w);
    *(ushort4*)&d[(size_t)i*4] = o;
  }
}

// ---------------------------------------------------------------------------
// V transpose: vtmp (bh, n, d) -> vt (bh, d, m=n) stride VTS.
// 64x64 LDS tile, coalesced 16B reads AND writes. Pad stride 66.
// ---------------------------------------------------------------------------
#define TVP 66
__global__ __launch_bounds__(256) void vtrans_kernel(
    const unsigned short* __restrict__ v, unsigned short* __restrict__ vt)
{
  __shared__ __align__(16) unsigned short T[64*TVP];
  const int tid = threadIdx.x;
  const int bh = blockIdx.y;
  const int n0 = blockIdx.x * 64;
  const s16x8 z8 = {0,0,0,0,0,0,0,0};
  {
    int r = tid >> 2, seg = tid & 3;
    int n = n0 + r;
    s16x8 a0 = z8, a1 = z8;
    if (n < SEQ) {
      const unsigned short* src = &v[((size_t)bh*SEQ + n)*DH + seg*16];
      a0 = *(const s16x8*)&src[0];
      a1 = *(const s16x8*)&src[8];
    }
    *(s16x8*)&T[r*TVP + seg*16]     = a0;
    *(s16x8*)&T[r*TVP + seg*16 + 8] = a1;
  }
  __syncthreads();
  {
    int d = tid >> 2, jseg = tid & 3;
    int jb = jseg * 16;
    unsigned short* dst = &vt[((size_t)bh*DH + d)*VTS + n0 + jb];
    if (n0 + jb + 15 < SEQ) {
      s16x8 b0, b1;
#pragma unroll
      for (int s = 0; s < 8; ++s) b0[s] = T[(jb + s)*TVP + d];
#pragma unroll
      for (int s = 0; s < 8; ++s) b1[s] = T[(jb + 8 + s)*TVP + d];
      *(s16x8*)&dst[0] = b0;
      *(s16x8*)&dst[8] = b1;
    } else {
      for (int s = 0; s < 16; ++s) {
        if (n0 + jb + s < SEQ) dst[s] = T[(jb + s)*TVP + d];
      }
    }
  }
}

// ---------------------------------------------------------------------------
// QKV GEMM: 64x128 tile (round-9-proven gemm64 structure: 1314 blocks =
// 5.1/CU vs 2.6/CU at 128^2), double-buffered LDS, T3 2-phase ordering.
// Identical K-step accumulation order to the 128^2 kernel -> bit-identical.
// Scatter epilogue: q/k/v coalesced (b,h,n,d) writes, per-j decomposition.
// LDS: A 2x4KB + B 2x8KB = 24KB.
// ---------------------------------------------------------------------------
#define GT 128
__global__ __launch_bounds__(256) void gemmqkv_kernel(
    const unsigned short* __restrict__ A, const unsigned short* __restrict__ Bm,
    unsigned short* __restrict__ Cq, unsigned short* __restrict__ Ck,
    unsigned short* __restrict__ Cv, int M)
{
  __shared__ __align__(16) unsigned short As[2][64*32];
  __shared__ __align__(16) unsigned short Bs[2][128*32];
  const int tid = threadIdx.x;
  const int wave = tid >> 6;
  const int lane = tid & 63;
  const int li = lane & 15, g = lane >> 4;
  const int r0 = blockIdx.y * 64, c0 = blockIdx.x * GT;

  const int rowA = tid >> 2, seg = tid & 3;          // 256 chunks of A
  const int rowB2 = (tid + 256) >> 2;                // B rows 64..127
  const unsigned short* ga  = &A [(size_t)(r0 + rowA)*EMB + seg*8];
  const unsigned short* gb1 = &Bm[(size_t)(c0 + rowA)*EMB + seg*8];
  const unsigned short* gb2 = &Bm[(size_t)(c0 + rowB2)*EMB + seg*8];

  f32x4 acc[4][2];
#pragma unroll
  for (int i = 0; i < 4; ++i)
#pragma unroll
    for (int j = 0; j < 2; ++j) { acc[i][j][0]=0.f; acc[i][j][1]=0.f; acc[i][j][2]=0.f; acc[i][j][3]=0.f; }

  gl_lds16(ga,  &As[0][wave*512]);
  gl_lds16(gb1, &Bs[0][wave*512]);
  gl_lds16(gb2, &Bs[0][2048 + wave*512]);

  int cur = 0;
  for (int k0 = 0; k0 < EMB; k0 += 32) {
    __syncthreads();   // drains gl_lds for buf[cur] (issued last iter)
    if (k0 + 32 < EMB) {
      int kn = k0 + 32;
      gl_lds16(ga + kn,  &As[cur^1][wave*512]);
      gl_lds16(gb1 + kn, &Bs[cur^1][wave*512]);
      gl_lds16(gb2 + kn, &Bs[cur^1][2048 + wave*512]);
    }

    s16x8 af[4], bfv[2];
#pragma unroll
    for (int i = 0; i < 4; ++i) af[i]  = *(const s16x8*)&As[cur][(i*16 + li)*32 + g*8];
#pragma unroll
    for (int j = 0; j < 2; ++j) bfv[j] = *(const s16x8*)&Bs[cur][(wave*32 + j*16 + li)*32 + g*8];
#pragma unroll
    for (int i = 0; i < 4; ++i)
#pragma unroll
      for (int j = 0; j < 2; ++j)
        acc[i][j] = __builtin_amdgcn_mfma_f32_16x16x32_bf16(af[i], bfv[j], acc[i][j], 0, 0, 0);
    cur ^= 1;
  }

  // per-j column decomposition; q/k/v share (b,h,n,d) addressing
  unsigned short* cb[2]; size_t coff[2];
#pragma unroll
  for (int j = 0; j < 2; ++j) {
    int col = c0 + wave*32 + j*16 + li;
    int t  = col / EMB;
    int ct = col - t*EMB;
    int h  = ct >> 6, dd = ct & 63;
    cb[j]   = (t == 0) ? Cq : (t == 1) ? Ck : Cv;
    coff[j] = (size_t)h*SEQ*DH + dd;
  }
#pragma unroll
  for (int i = 0; i < 4; ++i) {
    int rbase = r0 + i*16 + g*4;
#pragma unroll
    for (int rg = 0; rg < 4; ++rg) {
      int gr = rbase + rg;
      if (gr >= M) continue;
      int brow = gr / SEQ, nrow = gr - brow*SEQ;
      size_t roff = ((size_t)brow*NH)*SEQ*DH + (size_t)nrow*DH;
#pragma unroll
      for (int j = 0; j < 2; ++j)
        cb[j][roff + coff[j]] = f2bf(acc[i][j][rg]);
    }
  }
}

// ---------------------------------------------------------------------------
// Proj GEMM: 64x128 tile, fp32 output (round-9 proven, merged both chunks).
// ---------------------------------------------------------------------------
__global__ __launch_bounds__(256) void gemm64_kernel(
    const unsigned short* __restrict__ A, const unsigned short* __restrict__ Bm,
    float* __restrict__ Cf, int M, int N)
{
  __shared__ __align__(16) unsigned short As[2][64*32];
  __shared__ __align__(16) unsigned short Bs[2][128*32];
  const int tid = threadIdx.x;
  const int wave = tid >> 6;
  const int lane = tid & 63;
  const int li = lane & 15, g = lane >> 4;
  const int r0 = blockIdx.y * 64, c0 = blockIdx.x * GT;

  const int rowA = tid >> 2, seg = tid & 3;          // 256 chunks of A
  const int rowB2 = (tid + 256) >> 2;                // B rows 64..127
  const unsigned short* ga  = &A [(size_t)(r0 + rowA)*EMB + seg*8];
  const unsigned short* gb1 = &Bm[(size_t)(c0 + rowA)*EMB + seg*8];
  const unsigned short* gb2 = &Bm[(size_t)(c0 + rowB2)*EMB + seg*8];

  f32x4 acc[4][2];
#pragma unroll
  for (int i = 0; i < 4; ++i)
#pragma unroll
    for (int j = 0; j < 2; ++j) { acc[i][j][0]=0.f; acc[i][j][1]=0.f; acc[i][j][2]=0.f; acc[i][j][3]=0.f; }

  gl_lds16(ga,  &As[0][wave*512]);
  gl_lds16(gb1, &Bs[0][wave*512]);
  gl_lds16(gb2, &Bs[0][2048 + wave*512]);

  int cur = 0;
  for (int k0 = 0; k0 < EMB; k0 += 32) {
    __syncthreads();
    if (k0 + 32 < EMB) {
      int kn = k0 + 32;
      gl_lds16(ga + kn,  &As[cur^1][wave*512]);
      gl_lds16(gb1 + kn, &Bs[cur^1][wave*512]);
      gl_lds16(gb2 + kn, &Bs[cur^1][2048 + wave*512]);
    }

    s16x8 af[4], bfv[2];
#pragma unroll
    for (int i = 0; i < 4; ++i) af[i]  = *(const s16x8*)&As[cur][(i*16 + li)*32 + g*8];
#pragma unroll
    for (int j = 0; j < 2; ++j) bfv[j] = *(const s16x8*)&Bs[cur][(wave*32 + j*16 + li)*32 + g*8];
#pragma unroll
    for (int i = 0; i < 4; ++i)
#pragma unroll
      for (int j = 0; j < 2; ++j)
        acc[i][j] = __builtin_amdgcn_mfma_f32_16x16x32_bf16(af[i], bfv[j], acc[i][j], 0, 0, 0);
    cur ^= 1;
  }

#pragma unroll
  for (int i = 0; i < 4; ++i) {
    int rbase = r0 + i*16 + g*4;
#pragma unroll
    for (int rg = 0; rg < 4; ++rg) {
      int gr = rbase + rg;
      if (gr >= M) continue;
      float* crow = &Cf[(size_t)gr*N + c0 + wave*32 + li];
#pragma unroll
      for (int j = 0; j < 2; ++j) crow[j*16] = acc[i][j][rg];
    }
  }
}

// ---------------------------------------------------------------------------
// MFMA fused attention — round-8 NO-MAX kernel VERBATIM (81us proven).
// LDS: Ps 18688 + TBCS 3392 + red 256 + VXL/VYL 6400 = 28736.
// ---------------------------------------------------------------------------
#define TRB 16
#define SW 584

#define FOR_KT(X) X(0) X(1) X(2) X(3) X(4) X(5) X(6) X(7) X(8) X(9)

__global__ __launch_bounds__(256) void attn_kernel(
    const unsigned short* __restrict__ qg, const unsigned short* __restrict__ kg,
    const unsigned short* __restrict__ vtg,
    const float* __restrict__ qxe, const float* __restrict__ qye,
    const float* __restrict__ vxe, const float* __restrict__ vye,
    unsigned short* __restrict__ og)
{
  __shared__ __align__(16) unsigned short Ps[TRB][SW];
  __shared__ __align__(16) unsigned char  TBCS[3392];
  __shared__ __align__(16) float red[TRB][4];
  __shared__ __align__(16) unsigned short VXL[50*32];
  __shared__ __align__(16) unsigned short VYL[50*32];

  const int tid  = threadIdx.x;
  const int wave = tid >> 6, lane = tid & 63;
  const int li = lane & 15, gg = lane >> 4;
  const int bh = blockIdx.y;
  const int r0 = blockIdx.x * TRB;
  const size_t qkbase = (size_t)bh * SEQ * DH;
  const size_t vtbase = (size_t)bh * DH * VTS;
  const s16x8 z8 = {0,0,0,0,0,0,0,0};

  // ---- stage v-bias tables into LDS as bf16 (1600 entries each) ----
  for (int t4 = tid; t4 < 400; t4 += 256) {
    float4 a = ((const float4*)vxe)[t4];
    float4 b = ((const float4*)vye)[t4];
    ushort4 oa; oa.x=f2bf(a.x); oa.y=f2bf(a.y); oa.z=f2bf(a.z); oa.w=f2bf(a.w);
    ushort4 ob; ob.x=f2bf(b.x); ob.y=f2bf(b.y); ob.z=f2bf(b.z); ob.w=f2bf(b.w);
    ((ushort4*)VXL)[t4] = oa;
    ((ushort4*)VYL)[t4] = ob;
  }

  // ---- Q A-frags from global (kept resident through phase A) ----
  s16x8 qf0, qf1;
  {
    int n = r0 + li;
    qf0 = (n < SEQ) ? *(const s16x8*)&qg[qkbase + (size_t)n*DH + gg*8] : z8;
    qf1 = (n < SEQ) ? *(const s16x8*)&qg[qkbase + (size_t)n*DH + 32 + gg*8] : z8;
  }

  // ---- early K step-0 prefetch (lands during TB build / barrier 1) ----
  const unsigned short* kwv = &kg[qkbase + (size_t)(wave*16 + li)*DH];
  s16x8 kp0 = *(const s16x8*)&kwv[gg*8];
  s16x8 kp1 = *(const s16x8*)&kwv[32 + gg*8];

  // ---- bias dot tables via MFMA: qx_dot/qy_dot [16 rows][50 bins] bf16,
  //      row stride 104, y half at +52 (bank de-alias) ----
  unsigned short* TB = (unsigned short*)TBCS;
  {
    int bin = wave*16 + li;
    s16x8 bx = z8, by = z8;
    if (bin < 50) {
      float4 x0 = *(const float4*)&qxe[bin*32 + gg*8];
      float4 x1 = *(const float4*)&qxe[bin*32 + gg*8 + 4];
      float4 y0 = *(const float4*)&qye[bin*32 + gg*8];
      float4 y1 = *(const float4*)&qye[bin*32 + gg*8 + 4];
      bx[0]=f2bf(x0.x); bx[1]=f2bf(x0.y); bx[2]=f2bf(x0.z); bx[3]=f2bf(x0.w);
      bx[4]=f2bf(x1.x); bx[5]=f2bf(x1.y); bx[6]=f2bf(x1.z); bx[7]=f2bf(x1.w);
      by[0]=f2bf(y0.x); by[1]=f2bf(y0.y); by[2]=f2bf(y0.z); by[3]=f2bf(y0.w);
      by[4]=f2bf(y1.x); by[5]=f2bf(y1.y); by[6]=f2bf(y1.z); by[7]=f2bf(y1.w);
    }
    f32x4 ax0={0.f,0.f,0.f,0.f}, ay0={0.f,0.f,0.f,0.f};
    ax0 = __builtin_amdgcn_mfma_f32_16x16x32_bf16(qf0, bx, ax0, 0,0,0);
    ay0 = __builtin_amdgcn_mfma_f32_16x16x32_bf16(qf1, by, ay0, 0,0,0);
    if (bin < 50) {
#pragma unroll
      for (int rg = 0; rg < 4; ++rg) {
        TB[(gg*4+rg)*104      + bin] = f2bf(ax0[rg]);
        TB[(gg*4+rg)*104 + 52 + bin] = f2bf(ay0[rg]);
      }
    }
  }

  // row coords for bias (per rg)
  int xn[4], yn[4];
#pragma unroll
  for (int rg = 0; rg < 4; ++rg) {
    int n = r0 + gg*4 + rg;
    if (n > 0 && n <= SEQ) { xn[rg] = (n-1) % 24; yn[rg] = (n-1) / 24; }
    else { xn[rg] = 0; yn[rg] = 0; }
  }
  __syncthreads();   // barrier 1: TB + VXL/VYL visible

  // ---- Phase A+B merged: QK^T + bias -> exp -> Ps + Lp; K pipelined ----
  f32x4 LpA = {0.f,0.f,0.f,0.f};

#define KTSTEP(KT) do {                                                       \
    const int m0_ = (KT)*64;                                                  \
    s16x8 kc0_ = kp0, kc1_ = kp1;                                             \
    if ((KT) < 9) {                                                           \
      kp0 = *(const s16x8*)&kwv[(size_t)(m0_ + 64)*DH + gg*8];                \
      kp1 = *(const s16x8*)&kwv[(size_t)(m0_ + 64)*DH + 32 + gg*8];           \
    }                                                                         \
    f32x4 a0_ = {0.f,0.f,0.f,0.f};                                            \
    a0_ = __builtin_amdgcn_mfma_f32_16x16x32_bf16(qf0, kc0_, a0_, 0,0,0);     \
    a0_ = __builtin_amdgcn_mfma_f32_16x16x32_bf16(qf1, kc1_, a0_, 0,0,0);     \
    int m_ = m0_ + wave*16 + li;                                              \
    int xm_ = 0, ym_ = 0;                                                     \
    bool mv_ = (m_ > 0 && m_ < SEQ);                                          \
    if (mv_) { xm_ = (m_-1) % 24; ym_ = (m_-1) / 24; }                        \
    _Pragma("unroll")                                                         \
    for (int rg = 0; rg < 4; ++rg) {                                          \
      int nloc_ = gg*4 + rg; int n_ = r0 + nloc_;                             \
      float s_ = a0_[rg]; int xi_ = 0, yi_ = 0;                               \
      if (mv_ && n_ > 0) { xi_ = xm_ - xn[rg] + 25; yi_ = ym_ - yn[rg] + 25; }\
      s_ = (s_ + bf2f(TB[nloc_*104 + xi_]) + bf2f(TB[nloc_*104 + 52 + yi_])) * 0.125f; \
      float p_ = (m_ < SEQ) ? __expf(s_) : 0.f;                               \
      LpA[rg] += p_;                                                          \
      if (m_ < SW) Ps[nloc_][m_] = f2bf(p_);                                  \
    }                                                                         \
  } while (0);
  FOR_KT(KTSTEP)
#undef KTSTEP

  // ---- early V step-0 prefetch (rides through CS phase) ----
  const unsigned short* vwv = &vtg[vtbase + (size_t)(wave*16 + li)*VTS];
  s16x8 vp0 = *(const s16x8*)&vwv[gg*8];
  s16x8 vp1 = *(const s16x8*)&vwv[32 + gg*8];

  // ---- row-sum reduce ----
#pragma unroll
  for (int rg = 0; rg < 4; ++rg) {
    float s = LpA[rg];
    s += __shfl_xor(s, 1); s += __shfl_xor(s, 2);
    s += __shfl_xor(s, 4); s += __shfl_xor(s, 8);
    if (li == 0) red[gg*4 + rg][wave] = s;
  }
  __syncthreads();   // barrier 2: Ps complete; red sums ready; TB dead
  float* CS = (float*)TBCS;                            // [16][49]
  if (wave == 0 && li == 0) {
#pragma unroll
    for (int rg = 0; rg < 4; ++rg) {
      int nloc = gg*4 + rg;
      float4 r4 = *(float4*)&red[nloc][0];
      CS[nloc*49 + 48] = r4.x + r4.y + r4.z + r4.w;
    }
  }
  {
    int r = tid >> 4, kb = tid & 15;        // div-free: 16 threads per row
#pragma unroll
    for (int kk = 0; kk < 3; ++kk) {
      int k = kb + kk*16;
      float s = 0.f;
      if (k < 24) {
#pragma unroll
        for (int c2 = 0; c2 < 24; ++c2) s += bf2f(Ps[r][1 + c2*24 + k]);
      } else {
        int rw = k - 24;
#pragma unroll
        for (int c2 = 0; c2 < 24; ++c2) s += bf2f(Ps[r][1 + rw*24 + c2]);
      }
      CS[r*49 + k] = s;
    }
  }
  __syncthreads();   // barrier 3: CS complete (epilogue reads it)

  // ---- Phase C: O = P.V via MFMA, V + Ps pipelined; NO barriers ----
  f32x4 oa0 = {0.f,0.f,0.f,0.f};
  s16x8 ap0 = *(const s16x8*)&Ps[li][gg*8];
  s16x8 ap1 = *(const s16x8*)&Ps[li][32 + gg*8];
#pragma unroll
  for (int vt = 0; vt < 10; ++vt) {
    s16x8 vc0 = vp0, vc1 = vp1;
    s16x8 ac0 = ap0, ac1 = ap1;
    if (vt < 9) {
      int mn = (vt + 1)*64;
      vp0 = *(const s16x8*)&vwv[mn + gg*8];
      vp1 = *(const s16x8*)&vwv[mn + 32 + gg*8];
      if (vt < 8) {
        ap0 = *(const s16x8*)&Ps[li][mn + gg*8];
        ap1 = *(const s16x8*)&Ps[li][mn + 32 + gg*8];
      } else {
        ap0 = (gg == 0) ? *(const s16x8*)&Ps[li][576] : z8;   // probs 577..583 = 0
        ap1 = z8;
      }
    }
    oa0 = __builtin_amdgcn_mfma_f32_16x16x32_bf16(ac0, vc0, oa0, 0,0,0);
    oa0 = __builtin_amdgcn_mfma_f32_16x16x32_bf16(ac1, vc1, oa0, 0,0,0);
  }

  // ---- Epilogue: + v-bias (bf16 LDS tables), /L, write bf16 (B,N,H,D) ----
  {
    int d = wave*16 + li;
    const unsigned short* tabL = (d < 32) ? VXL : VYL;
    int dd = d & 31;
    bool useX = (d < 32);
    int bI = bh / NH, hI = bh - bI*NH;
#pragma unroll
    for (int rg = 0; rg < 4; ++rg) {
      int nloc = gg*4 + rg;
      int n = r0 + nloc;
      if (n >= SEQ) continue;
      float Lr = CS[nloc*49 + 48];
      float bias;
      if (n == 0) {
        bias = Lr * bf2f(tabL[dd]);
      } else {
        int cn = useX ? ((n-1) % 24) : ((n-1) / 24);
        const unsigned short* trow = &tabL[(25 - cn)*32 + dd];
        const float* csrow = &CS[nloc*49 + (useX ? 0 : 24)];
        float b0 = bf2f(Ps[nloc][0]) * bf2f(tabL[dd]);
        float b1 = 0.f, b2 = 0.f, b3 = 0.f;
#pragma unroll
        for (int c = 0; c < 24; c += 4) {
          b0 = fmaf(csrow[c    ], bf2f(trow[(c    )*32]), b0);
          b1 = fmaf(csrow[c + 1], bf2f(trow[(c + 1)*32]), b1);
          b2 = fmaf(csrow[c + 2], bf2f(trow[(c + 2)*32]), b2);
          b3 = fmaf(csrow[c + 3], bf2f(trow[(c + 3)*32]), b3);
        }
        bias = (b0 + b1) + (b2 + b3);
      }
      float o = (oa0[rg] + bias) / Lr;
      og[(((size_t)bI*SEQ + n)*NH + hI)*DH + d] = f2bf(o);
    }
  }
}

// ---------------------------------------------------------------------------
// ws (ushorts): q 3.545M, k 3.545M, vt 3.637M, ows 7.090M (BOTH chunks),
// xbf 3.545M, wqkv 1.769M, wproj 0.590M, vtmp 3.545M => 54.5 MB (< 56.7).
// ---------------------------------------------------------------------------
extern "C" void kernel_launch(void* const* d_in, const int* in_sizes, int n_in,
                              void* d_out, int out_size, void* d_ws, size_t ws_size,
                              hipStream_t stream)
{
  const float* x     = (const float*)d_in[0];
  const float* qkvw  = (const float*)d_in[1];
  const float* projw = (const float*)d_in[2];
  const float* qxe   = (const float*)d_in[3];
  const float* qye   = (const float*)d_in[4];
  const float* vxe   = (const float*)d_in[5];
  const float* vye   = (const float*)d_in[6];
  float* out = (float*)d_out;

  const size_t SLc = (size_t)BHC * SEQ * DH;        // 3,545,088
  const size_t VTL = (size_t)BHC * DH * VTS;        // 3,637,248
  unsigned short* qws   = (unsigned short*)d_ws;
  unsigned short* kws   = qws + SLc;
  unsigned short* vtws  = kws + SLc;
  unsigned short* ows   = vtws + VTL;               // 2*SLc (both chunks)
  unsigned short* xbf   = ows + 2*SLc;
  unsigned short* wqkv  = xbf + SLc;
  unsigned short* wproj = wqkv + (size_t)3*EMB*EMB;
  unsigned short* vtmp  = wproj + (size_t)EMB*EMB;

  cast_kernel<<<(3*EMB*EMB/4 + 255)/256, 256, 0, stream>>>(qkvw, wqkv, 3*EMB*EMB/4);
  cast_kernel<<<(EMB*EMB/4 + 255)/256, 256, 0, stream>>>(projw, wproj, EMB*EMB/4);

  dim3 g1(3*EMB/GT, (MC + 63)/64);       // 18 x 73: qkv GEMM (BM=64)
  dim3 gt(10, BHC);                      // V transpose: 10 n-tiles x 96 bh
  dim3 g2((SEQ + TRB - 1)/TRB, BHC);     // 37 x 96
  dim3 g3(EMB/GT, (2*MC + 63)/64);       // 6 x 145: merged proj GEMM

  for (int c = 0; c < NC; ++c) {
    const float* xc = x + (size_t)c * MC * EMB;
    cast_kernel<<<(MC*EMB/4 + 255)/256, 256, 0, stream>>>(xc, xbf, MC*EMB/4);
    gemmqkv_kernel<<<g1, 256, 0, stream>>>(xbf, wqkv, qws, kws, vtmp, MC);
    vtrans_kernel<<<gt, 256, 0, stream>>>(vtmp, vtws);
    attn_kernel<<<g2, 256, 0, stream>>>(qws, kws, vtws, qxe, qye, vxe, vye,
                                        ows + (size_t)c * SLc);
  }
  // one merged proj GEMM over both chunks (depends only on attn outputs)
  gemm64_kernel<<<g3, 256, 0, stream>>>(ows, wproj, out, 2*MC, EMB);
}

// Round 11
// 330.802 us; speedup vs baseline: 1.0890x; 1.0890x over previous
//
#include <hip/hip_runtime.h>
#include <math.h>

#define SEQ 577
#define NH 12
#define DH 64
#define EMB 768
#define NBATCH 16
#define NC 2
#define BC (NBATCH/NC)
#define MC (BC*SEQ)      // 4616 rows per chunk
#define BHC (BC*NH)      // 96 (b,h) per chunk
#define VTS 592          // vt row stride in m (16 ushort aligned, >= 577)

typedef float f32x4 __attribute__((ext_vector_type(4)));
typedef short s16x8 __attribute__((ext_vector_type(8)));

__device__ __forceinline__ float bf2f(unsigned short u) {
  union { unsigned int i; float f; } c; c.i = ((unsigned int)u) << 16; return c.f;
}
__device__ __forceinline__ unsigned short f2bf(float f) {
  union { float f; unsigned int i; } c; c.f = f;
  unsigned int r = c.i + 0x7FFFu + ((c.i >> 16) & 1u);   // round-nearest-even
  return (unsigned short)(r >> 16);
}

// Async global->LDS, 16B per lane. LDS dest is wave-uniform base + lane*16.
__device__ __forceinline__ void gl_lds16(const unsigned short* g, unsigned short* l) {
  __builtin_amdgcn_global_load_lds(
      (const __attribute__((address_space(1))) unsigned int*)g,
      (__attribute__((address_space(3))) unsigned int*)l, 16, 0, 0);
}

// ---------------------------------------------------------------------------
__global__ __launch_bounds__(256) void cast_kernel(
    const float* __restrict__ s, unsigned short* __restrict__ d, int n4)
{
  int i = blockIdx.x * 256 + threadIdx.x;
  if (i < n4) {
    float4 v = *(const float4*)&s[(size_t)i*4];
    ushort4 o; o.x = f2bf(v.x); o.y = f2bf(v.y); o.z = f2bf(v.z); o.w = f2bf(v.w);
    *(ushort4*)&d[(size_t)i*4] = o;
  }
}

// ---------------------------------------------------------------------------
// V transpose: vtmp (bh, n, d) -> vt (bh, d, m=n) stride VTS.
// 64x64 LDS tile, coalesced 16B reads AND writes. Pad stride 66.
// ---------------------------------------------------------------------------
#define TVP 66
__global__ __launch_bounds__(256) void vtrans_kernel(
    const unsigned short* __restrict__ v, unsigned short* __restrict__ vt)
{
  __shared__ __align__(16) unsigned short T[64*TVP];
  const int tid = threadIdx.x;
  const int bh = blockIdx.y;
  const int n0 = blockIdx.x * 64;
  const s16x8 z8 = {0,0,0,0,0,0,0,0};
  {
    int r = tid >> 2, seg = tid & 3;
    int n = n0 + r;
    s16x8 a0 = z8, a1 = z8;
    if (n < SEQ) {
      const unsigned short* src = &v[((size_t)bh*SEQ + n)*DH + seg*16];
      a0 = *(const s16x8*)&src[0];
      a1 = *(const s16x8*)&src[8];
    }
    *(s16x8*)&T[r*TVP + seg*16]     = a0;
    *(s16x8*)&T[r*TVP + seg*16 + 8] = a1;
  }
  __syncthreads();
  {
    int d = tid >> 2, jseg = tid & 3;
    int jb = jseg * 16;
    unsigned short* dst = &vt[((size_t)bh*DH + d)*VTS + n0 + jb];
    if (n0 + jb + 15 < SEQ) {
      s16x8 b0, b1;
#pragma unroll
      for (int s = 0; s < 8; ++s) b0[s] = T[(jb + s)*TVP + d];
#pragma unroll
      for (int s = 0; s < 8; ++s) b1[s] = T[(jb + 8 + s)*TVP + d];
      *(s16x8*)&dst[0] = b0;
      *(s16x8*)&dst[8] = b1;
    } else {
      for (int s = 0; s < 16; ++s) {
        if (n0 + jb + s < SEQ) dst[s] = T[(jb + s)*TVP + d];
      }
    }
  }
}

// ---------------------------------------------------------------------------
// bf16 MFMA GEMM (NT), 128x128 tile, double-buffered LDS (T3 2-phase).
// PROVEN round-9 kernel (BM=64 variant regressed at 2.6 blocks/CU — the
// tile's arithmetic intensity matters once occupancy is adequate).
// mode 0: scatter q/k/v coalesced (b,h,n,d). mode 1: fp32 row-major.
// ---------------------------------------------------------------------------
#define GT 128
__global__ __launch_bounds__(256) void gemm_bf16(
    const unsigned short* __restrict__ A, const unsigned short* __restrict__ Bm,
    unsigned short* __restrict__ Cq, unsigned short* __restrict__ Ck,
    unsigned short* __restrict__ Cv, float* __restrict__ Cf,
    int M, int N, int mode)
{
  __shared__ __align__(16) unsigned short AsF[2][GT*32];
  __shared__ __align__(16) unsigned short BsF[2][GT*32];
  const int tid = threadIdx.x;
  const int wave = tid >> 6;
  const int lane = tid & 63;
  const int wr = wave >> 1, wc = wave & 1;
  const int li = lane & 15, g = lane >> 4;
  const int r0 = blockIdx.y * GT, c0 = blockIdx.x * GT;

  const int row1 = tid >> 2,          seg1 = tid & 3;
  const int row2 = (tid + 256) >> 2,  seg2 = tid & 3;
  const unsigned short* ga1 = &A [(size_t)(r0 + row1)*EMB + seg1*8];
  const unsigned short* ga2 = &A [(size_t)(r0 + row2)*EMB + seg2*8];
  const unsigned short* gb1 = &Bm[(size_t)(c0 + row1)*EMB + seg1*8];
  const unsigned short* gb2 = &Bm[(size_t)(c0 + row2)*EMB + seg2*8];

  f32x4 acc[4][4];
#pragma unroll
  for (int i = 0; i < 4; ++i)
#pragma unroll
    for (int j = 0; j < 4; ++j) { acc[i][j][0]=0.f; acc[i][j][1]=0.f; acc[i][j][2]=0.f; acc[i][j][3]=0.f; }

  // prologue: stage tile 0 into buffer 0
  gl_lds16(ga1, &AsF[0][wave*512]);
  gl_lds16(ga2, &AsF[0][2048 + wave*512]);
  gl_lds16(gb1, &BsF[0][wave*512]);
  gl_lds16(gb2, &BsF[0][2048 + wave*512]);

  int cur = 0;
  for (int k0 = 0; k0 < EMB; k0 += 32) {
    __syncthreads();   // drains gl_lds for buf[cur] (issued last iter, flew
                       // under last iter's compute); syncs buf reuse
    if (k0 + 32 < EMB) {
      int kn = k0 + 32;
      gl_lds16(ga1 + kn, &AsF[cur^1][wave*512]);
      gl_lds16(ga2 + kn, &AsF[cur^1][2048 + wave*512]);
      gl_lds16(gb1 + kn, &BsF[cur^1][wave*512]);
      gl_lds16(gb2 + kn, &BsF[cur^1][2048 + wave*512]);
    }

    s16x8 af[4], bfv[4];
#pragma unroll
    for (int i = 0; i < 4; ++i) af[i]  = *(const s16x8*)&AsF[cur][(wr*64 + i*16 + li)*32 + g*8];
#pragma unroll
    for (int j = 0; j < 4; ++j) bfv[j] = *(const s16x8*)&BsF[cur][(wc*64 + j*16 + li)*32 + g*8];
#pragma unroll
    for (int i = 0; i < 4; ++i)
#pragma unroll
      for (int j = 0; j < 4; ++j)
        acc[i][j] = __builtin_amdgcn_mfma_f32_16x16x32_bf16(af[i], bfv[j], acc[i][j], 0, 0, 0);
    cur ^= 1;
  }

  if (mode == 1) {
#pragma unroll
    for (int i = 0; i < 4; ++i) {
      int rbase = r0 + wr*64 + i*16 + g*4;
#pragma unroll
      for (int rg = 0; rg < 4; ++rg) {
        int gr = rbase + rg;
        if (gr >= M) continue;
        float* crow = &Cf[(size_t)gr*N + c0 + wc*64 + li];
#pragma unroll
        for (int j = 0; j < 4; ++j) crow[j*16] = acc[i][j][rg];
      }
    }
  } else {
    // per-j column decomposition; all targets share (b,h,n,d) addressing now
    unsigned short* cb[4]; size_t coff[4];
#pragma unroll
    for (int j = 0; j < 4; ++j) {
      int col = c0 + wc*64 + j*16 + li;
      int t  = col / EMB;
      int ct = col - t*EMB;
      int h  = ct >> 6, dd = ct & 63;
      cb[j]   = (t == 0) ? Cq : (t == 1) ? Ck : Cv;
      coff[j] = (size_t)h*SEQ*DH + dd;
    }
#pragma unroll
    for (int i = 0; i < 4; ++i) {
      int rbase = r0 + wr*64 + i*16 + g*4;
#pragma unroll
      for (int rg = 0; rg < 4; ++rg) {
        int gr = rbase + rg;
        if (gr >= M) continue;
        int brow = gr / SEQ, nrow = gr - brow*SEQ;
        size_t roff = ((size_t)brow*NH)*SEQ*DH + (size_t)nrow*DH;
#pragma unroll
        for (int j = 0; j < 4; ++j)
          cb[j][roff + coff[j]] = f2bf(acc[i][j][rg]);
      }
    }
  }
}

// ---------------------------------------------------------------------------
// Proj GEMM: 64x128 tile, fp32 output (round-9 proven, merged both chunks;
// BM=64 is right HERE because 128^2 gave only 0.87 blocks/CU).
// ---------------------------------------------------------------------------
__global__ __launch_bounds__(256) void gemm64_kernel(
    const unsigned short* __restrict__ A, const unsigned short* __restrict__ Bm,
    float* __restrict__ Cf, int M, int N)
{
  __shared__ __align__(16) unsigned short As[2][64*32];
  __shared__ __align__(16) unsigned short Bs[2][128*32];
  const int tid = threadIdx.x;
  const int wave = tid >> 6;
  const int lane = tid & 63;
  const int li = lane & 15, g = lane >> 4;
  const int r0 = blockIdx.y * 64, c0 = blockIdx.x * GT;

  const int rowA = tid >> 2, seg = tid & 3;          // 256 chunks of A
  const int rowB2 = (tid + 256) >> 2;                // B rows 64..127
  const unsigned short* ga  = &A [(size_t)(r0 + rowA)*EMB + seg*8];
  const unsigned short* gb1 = &Bm[(size_t)(c0 + rowA)*EMB + seg*8];
  const unsigned short* gb2 = &Bm[(size_t)(c0 + rowB2)*EMB + seg*8];

  f32x4 acc[4][2];
#pragma unroll
  for (int i = 0; i < 4; ++i)
#pragma unroll
    for (int j = 0; j < 2; ++j) { acc[i][j][0]=0.f; acc[i][j][1]=0.f; acc[i][j][2]=0.f; acc[i][j][3]=0.f; }

  gl_lds16(ga,  &As[0][wave*512]);
  gl_lds16(gb1, &Bs[0][wave*512]);
  gl_lds16(gb2, &Bs[0][2048 + wave*512]);

  int cur = 0;
  for (int k0 = 0; k0 < EMB; k0 += 32) {
    __syncthreads();
    if (k0 + 32 < EMB) {
      int kn = k0 + 32;
      gl_lds16(ga + kn,  &As[cur^1][wave*512]);
      gl_lds16(gb1 + kn, &Bs[cur^1][wave*512]);
      gl_lds16(gb2 + kn, &Bs[cur^1][2048 + wave*512]);
    }

    s16x8 af[4], bfv[2];
#pragma unroll
    for (int i = 0; i < 4; ++i) af[i]  = *(const s16x8*)&As[cur][(i*16 + li)*32 + g*8];
#pragma unroll
    for (int j = 0; j < 2; ++j) bfv[j] = *(const s16x8*)&Bs[cur][(wave*32 + j*16 + li)*32 + g*8];
#pragma unroll
    for (int i = 0; i < 4; ++i)
#pragma unroll
      for (int j = 0; j < 2; ++j)
        acc[i][j] = __builtin_amdgcn_mfma_f32_16x16x32_bf16(af[i], bfv[j], acc[i][j], 0, 0, 0);
    cur ^= 1;
  }

#pragma unroll
  for (int i = 0; i < 4; ++i) {
    int rbase = r0 + i*16 + g*4;
#pragma unroll
    for (int rg = 0; rg < 4; ++rg) {
      int gr = rbase + rg;
      if (gr >= M) continue;
      float* crow = &Cf[(size_t)gr*N + c0 + wave*32 + li];
#pragma unroll
      for (int j = 0; j < 2; ++j) crow[j*16] = acc[i][j][rg];
    }
  }
}

// ---------------------------------------------------------------------------
// MFMA fused attention — round-8 NO-MAX kernel + XCD-aware block swizzle:
//  Raw grid (37, 96) round-robins the 37 q-blocks of each bh across the 8
//  XCDs, so each XCD's L2 fetched its own K/V copy (FETCH 59.9 MB vs ~22
//  ideal, 2.8x). Remap: XCD x (= raw%8) owns bhs == x (mod 8); one bh's 37
//  blocks stay contiguous on one XCD -> K/V/Q (224 KB/bh x 12 bh = 2.7 MB)
//  L2-resident. Bijection: raw = ((bh>>3)*37 + bx)*8 + (bh&7).
// LDS: Ps 18688 + TBCS 3392 + red 256 + VXL/VYL 6400 = 28736.
// ---------------------------------------------------------------------------
#define TRB 16
#define SW 584

#define FOR_KT(X) X(0) X(1) X(2) X(3) X(4) X(5) X(6) X(7) X(8) X(9)

__global__ __launch_bounds__(256) void attn_kernel(
    const unsigned short* __restrict__ qg, const unsigned short* __restrict__ kg,
    const unsigned short* __restrict__ vtg,
    const float* __restrict__ qxe, const float* __restrict__ qye,
    const float* __restrict__ vxe, const float* __restrict__ vye,
    unsigned short* __restrict__ og)
{
  __shared__ __align__(16) unsigned short Ps[TRB][SW];
  __shared__ __align__(16) unsigned char  TBCS[3392];
  __shared__ __align__(16) float red[TRB][4];
  __shared__ __align__(16) unsigned short VXL[50*32];
  __shared__ __align__(16) unsigned short VYL[50*32];

  const int tid  = threadIdx.x;
  const int wave = tid >> 6, lane = tid & 63;
  const int li = lane & 15, gg = lane >> 4;
  // ---- XCD-aware swizzle (pure permutation of (bx, bh)) ----
  const int raw = blockIdx.x + 37 * blockIdx.y;
  const int xcd = raw & 7;
  const int jj  = raw >> 3;            // 0..443
  const int bh  = xcd + 8 * (jj / 37); // XCD x serves bhs == x mod 8
  const int r0  = (jj % 37) * TRB;
  const size_t qkbase = (size_t)bh * SEQ * DH;
  const size_t vtbase = (size_t)bh * DH * VTS;
  const s16x8 z8 = {0,0,0,0,0,0,0,0};

  // ---- stage v-bias tables into LDS as bf16 (1600 entries each) ----
  for (int t4 = tid; t4 < 400; t4 += 256) {
    float4 a = ((const float4*)vxe)[t4];
    float4 b = ((const float4*)vye)[t4];
    ushort4 oa; oa.x=f2bf(a.x); oa.y=f2bf(a.y); oa.z=f2bf(a.z); oa.w=f2bf(a.w);
    ushort4 ob; ob.x=f2bf(b.x); ob.y=f2bf(b.y); ob.z=f2bf(b.z); ob.w=f2bf(b.w);
    ((ushort4*)VXL)[t4] = oa;
    ((ushort4*)VYL)[t4] = ob;
  }

  // ---- Q A-frags from global (kept resident through phase A) ----
  s16x8 qf0, qf1;
  {
    int n = r0 + li;
    qf0 = (n < SEQ) ? *(const s16x8*)&qg[qkbase + (size_t)n*DH + gg*8] : z8;
    qf1 = (n < SEQ) ? *(const s16x8*)&qg[qkbase + (size_t)n*DH + 32 + gg*8] : z8;
  }

  // ---- early K step-0 prefetch (lands during TB build / barrier 1) ----
  const unsigned short* kwv = &kg[qkbase + (size_t)(wave*16 + li)*DH];
  s16x8 kp0 = *(const s16x8*)&kwv[gg*8];
  s16x8 kp1 = *(const s16x8*)&kwv[32 + gg*8];

  // ---- bias dot tables via MFMA: qx_dot/qy_dot [16 rows][50 bins] bf16,
  //      row stride 104, y half at +52 (bank de-alias) ----
  unsigned short* TB = (unsigned short*)TBCS;
  {
    int bin = wave*16 + li;
    s16x8 bx = z8, by = z8;
    if (bin < 50) {
      float4 x0 = *(const float4*)&qxe[bin*32 + gg*8];
      float4 x1 = *(const float4*)&qxe[bin*32 + gg*8 + 4];
      float4 y0 = *(const float4*)&qye[bin*32 + gg*8];
      float4 y1 = *(const float4*)&qye[bin*32 + gg*8 + 4];
      bx[0]=f2bf(x0.x); bx[1]=f2bf(x0.y); bx[2]=f2bf(x0.z); bx[3]=f2bf(x0.w);
      bx[4]=f2bf(x1.x); bx[5]=f2bf(x1.y); bx[6]=f2bf(x1.z); bx[7]=f2bf(x1.w);
      by[0]=f2bf(y0.x); by[1]=f2bf(y0.y); by[2]=f2bf(y0.z); by[3]=f2bf(y0.w);
      by[4]=f2bf(y1.x); by[5]=f2bf(y1.y); by[6]=f2bf(y1.z); by[7]=f2bf(y1.w);
    }
    f32x4 ax0={0.f,0.f,0.f,0.f}, ay0={0.f,0.f,0.f,0.f};
    ax0 = __builtin_amdgcn_mfma_f32_16x16x32_bf16(qf0, bx, ax0, 0,0,0);
    ay0 = __builtin_amdgcn_mfma_f32_16x16x32_bf16(qf1, by, ay0, 0,0,0);
    if (bin < 50) {
#pragma unroll
      for (int rg = 0; rg < 4; ++rg) {
        TB[(gg*4+rg)*104      + bin] = f2bf(ax0[rg]);
        TB[(gg*4+rg)*104 + 52 + bin] = f2bf(ay0[rg]);
      }
    }
  }

  // row coords for bias (per rg)
  int xn[4], yn[4];
#pragma unroll
  for (int rg = 0; rg < 4; ++rg) {
    int n = r0 + gg*4 + rg;
    if (n > 0 && n <= SEQ) { xn[rg] = (n-1) % 24; yn[rg] = (n-1) / 24; }
    else { xn[rg] = 0; yn[rg] = 0; }
  }
  __syncthreads();   // barrier 1: TB + VXL/VYL visible

  // ---- Phase A+B merged: QK^T + bias -> exp -> Ps + Lp; K pipelined ----
  f32x4 LpA = {0.f,0.f,0.f,0.f};

#define KTSTEP(KT) do {                                                       \
    const int m0_ = (KT)*64;                                                  \
    s16x8 kc0_ = kp0, kc1_ = kp1;                                             \
    if ((KT) < 9) {                                                           \
      kp0 = *(const s16x8*)&kwv[(size_t)(m0_ + 64)*DH + gg*8];                \
      kp1 = *(const s16x8*)&kwv[(size_t)(m0_ + 64)*DH + 32 + gg*8];           \
    }                                                                         \
    f32x4 a0_ = {0.f,0.f,0.f,0.f};                                            \
    a0_ = __builtin_amdgcn_mfma_f32_16x16x32_bf16(qf0, kc0_, a0_, 0,0,0);     \
    a0_ = __builtin_amdgcn_mfma_f32_16x16x32_bf16(qf1, kc1_, a0_, 0,0,0);     \
    int m_ = m0_ + wave*16 + li;                                              \
    int xm_ = 0, ym_ = 0;                                                     \
    bool mv_ = (m_ > 0 && m_ < SEQ);                                          \
    if (mv_) { xm_ = (m_-1) % 24; ym_ = (m_-1) / 24; }                        \
    _Pragma("unroll")                                                         \
    for (int rg = 0; rg < 4; ++rg) {                                          \
      int nloc_ = gg*4 + rg; int n_ = r0 + nloc_;                             \
      float s_ = a0_[rg]; int xi_ = 0, yi_ = 0;                               \
      if (mv_ && n_ > 0) { xi_ = xm_ - xn[rg] + 25; yi_ = ym_ - yn[rg] + 25; }\
      s_ = (s_ + bf2f(TB[nloc_*104 + xi_]) + bf2f(TB[nloc_*104 + 52 + yi_])) * 0.125f; \
      float p_ = (m_ < SEQ) ? __expf(s_) : 0.f;                               \
      LpA[rg] += p_;                                                          \
      if (m_ < SW) Ps[nloc_][m_] = f2bf(p_);                                  \
    }                                                                         \
  } while (0);
  FOR_KT(KTSTEP)
#undef KTSTEP

  // ---- early V step-0 prefetch (rides through CS phase) ----
  const unsigned short* vwv = &vtg[vtbase + (size_t)(wave*16 + li)*VTS];
  s16x8 vp0 = *(const s16x8*)&vwv[gg*8];
  s16x8 vp1 = *(const s16x8*)&vwv[32 + gg*8];

  // ---- row-sum reduce ----
#pragma unroll
  for (int rg = 0; rg < 4; ++rg) {
    float s = LpA[rg];
    s += __shfl_xor(s, 1); s += __shfl_xor(s, 2);
    s += __shfl_xor(s, 4); s += __shfl_xor(s, 8);
    if (li == 0) red[gg*4 + rg][wave] = s;
  }
  __syncthreads();   // barrier 2: Ps complete; red sums ready; TB dead
  float* CS = (float*)TBCS;                            // [16][49]
  if (wave == 0 && li == 0) {
#pragma unroll
    for (int rg = 0; rg < 4; ++rg) {
      int nloc = gg*4 + rg;
      float4 r4 = *(float4*)&red[nloc][0];
      CS[nloc*49 + 48] = r4.x + r4.y + r4.z + r4.w;
    }
  }
  {
    int r = tid >> 4, kb = tid & 15;        // div-free: 16 threads per row
#pragma unroll
    for (int kk = 0; kk < 3; ++kk) {
      int k = kb + kk*16;
      float s = 0.f;
      if (k < 24) {
#pragma unroll
        for (int c2 = 0; c2 < 24; ++c2) s += bf2f(Ps[r][1 + c2*24 + k]);
      } else {
        int rw = k - 24;
#pragma unroll
        for (int c2 = 0; c2 < 24; ++c2) s += bf2f(Ps[r][1 + rw*24 + c2]);
      }
      CS[r*49 + k] = s;
    }
  }
  __syncthreads();   // barrier 3: CS complete (epilogue reads it)

  // ---- Phase C: O = P.V via MFMA, V + Ps pipelined; NO barriers ----
  f32x4 oa0 = {0.f,0.f,0.f,0.f};
  s16x8 ap0 = *(const s16x8*)&Ps[li][gg*8];
  s16x8 ap1 = *(const s16x8*)&Ps[li][32 + gg*8];
#pragma unroll
  for (int vt = 0; vt < 10; ++vt) {
    s16x8 vc0 = vp0, vc1 = vp1;
    s16x8 ac0 = ap0, ac1 = ap1;
    if (vt < 9) {
      int mn = (vt + 1)*64;
      vp0 = *(const s16x8*)&vwv[mn + gg*8];
      vp1 = *(const s16x8*)&vwv[mn + 32 + gg*8];
      if (vt < 8) {
        ap0 = *(const s16x8*)&Ps[li][mn + gg*8];
        ap1 = *(const s16x8*)&Ps[li][mn + 32 + gg*8];
      } else {
        ap0 = (gg == 0) ? *(const s16x8*)&Ps[li][576] : z8;   // probs 577..583 = 0
        ap1 = z8;
      }
    }
    oa0 = __builtin_amdgcn_mfma_f32_16x16x32_bf16(ac0, vc0, oa0, 0,0,0);
    oa0 = __builtin_amdgcn_mfma_f32_16x16x32_bf16(ac1, vc1, oa0, 0,0,0);
  }

  // ---- Epilogue: + v-bias (bf16 LDS tables), /L, write bf16 (B,N,H,D) ----
  {
    int d = wave*16 + li;
    const unsigned short* tabL = (d < 32) ? VXL : VYL;
    int dd = d & 31;
    bool useX = (d < 32);
    int bI = bh / NH, hI = bh - bI*NH;
#pragma unroll
    for (int rg = 0; rg < 4; ++rg) {
      int nloc = gg*4 + rg;
      int n = r0 + nloc;
      if (n >= SEQ) continue;
      float Lr = CS[nloc*49 + 48];
      float bias;
      if (n == 0) {
        bias = Lr * bf2f(tabL[dd]);
      } else {
        int cn = useX ? ((n-1) % 24) : ((n-1) / 24);
        const unsigned short* trow = &tabL[(25 - cn)*32 + dd];
        const float* csrow = &CS[nloc*49 + (useX ? 0 : 24)];
        float b0 = bf2f(Ps[nloc][0]) * bf2f(tabL[dd]);
        float b1 = 0.f, b2 = 0.f, b3 = 0.f;
#pragma unroll
        for (int c = 0; c < 24; c += 4) {
          b0 = fmaf(csrow[c    ], bf2f(trow[(c    )*32]), b0);
          b1 = fmaf(csrow[c + 1], bf2f(trow[(c + 1)*32]), b1);
          b2 = fmaf(csrow[c + 2], bf2f(trow[(c + 2)*32]), b2);
          b3 = fmaf(csrow[c + 3], bf2f(trow[(c + 3)*32]), b3);
        }
        bias = (b0 + b1) + (b2 + b3);
      }
      float o = (oa0[rg] + bias) / Lr;
      og[(((size_t)bI*SEQ + n)*NH + hI)*DH + d] = f2bf(o);
    }
  }
}

// ---------------------------------------------------------------------------
// ws (ushorts): q 3.545M, k 3.545M, vt 3.637M, ows 7.090M (BOTH chunks),
// xbf 3.545M, wqkv 1.769M, wproj 0.590M, vtmp 3.545M => 54.5 MB (< 56.7).
// ---------------------------------------------------------------------------
extern "C" void kernel_launch(void* const* d_in, const int* in_sizes, int n_in,
                              void* d_out, int out_size, void* d_ws, size_t ws_size,
                              hipStream_t stream)
{
  const float* x     = (const float*)d_in[0];
  const float* qkvw  = (const float*)d_in[1];
  const float* projw = (const float*)d_in[2];
  const float* qxe   = (const float*)d_in[3];
  const float* qye   = (const float*)d_in[4];
  const float* vxe   = (const float*)d_in[5];
  const float* vye   = (const float*)d_in[6];
  float* out = (float*)d_out;

  const size_t SLc = (size_t)BHC * SEQ * DH;        // 3,545,088
  const size_t VTL = (size_t)BHC * DH * VTS;        // 3,637,248
  unsigned short* qws   = (unsigned short*)d_ws;
  unsigned short* kws   = qws + SLc;
  unsigned short* vtws  = kws + SLc;
  unsigned short* ows   = vtws + VTL;               // 2*SLc (both chunks)
  unsigned short* xbf   = ows + 2*SLc;
  unsigned short* wqkv  = xbf + SLc;
  unsigned short* wproj = wqkv + (size_t)3*EMB*EMB;
  unsigned short* vtmp  = wproj + (size_t)EMB*EMB;

  cast_kernel<<<(3*EMB*EMB/4 + 255)/256, 256, 0, stream>>>(qkvw, wqkv, 3*EMB*EMB/4);
  cast_kernel<<<(EMB*EMB/4 + 255)/256, 256, 0, stream>>>(projw, wproj, EMB*EMB/4);

  dim3 g1(3*EMB/GT, (MC + GT - 1)/GT);   // 18 x 37: qkv GEMM (128^2, proven)
  dim3 gt(10, BHC);                      // V transpose: 10 n-tiles x 96 bh
  dim3 g2((SEQ + TRB - 1)/TRB, BHC);     // 37 x 96
  dim3 g3(EMB/GT, (2*MC + 63)/64);       // 6 x 145: merged proj GEMM

  for (int c = 0; c < NC; ++c) {
    const float* xc = x + (size_t)c * MC * EMB;
    cast_kernel<<<(MC*EMB/4 + 255)/256, 256, 0, stream>>>(xc, xbf, MC*EMB/4);
    gemm_bf16<<<g1, 256, 0, stream>>>(xbf, wqkv, qws, kws, vtmp, nullptr, MC, 3*EMB, 0);
    vtrans_kernel<<<gt, 256, 0, stream>>>(vtmp, vtws);
    attn_kernel<<<g2, 256, 0, stream>>>(qws, kws, vtws, qxe, qye, vxe, vye,
                                        ows + (size_t)c * SLc);
  }
  // one merged proj GEMM over both chunks (depends only on attn outputs)
  gemm64_kernel<<<g3, 256, 0, stream>>>(ows, wproj, out, 2*MC, EMB);
}

// Round 12
// 327.482 us; speedup vs baseline: 1.1001x; 1.0101x over previous
//
#include <hip/hip_runtime.h>
#include <math.h>

#define SEQ 577
#define NH 12
#define DH 64
#define EMB 768
#define NBATCH 16
#define NC 2
#define BC (NBATCH/NC)
#define MC (BC*SEQ)      // 4616 rows per chunk
#define BHC (BC*NH)      // 96 (b,h) per chunk
#define VTS 592          // vt row stride in m (16 ushort aligned, >= 577)

typedef float f32x4 __attribute__((ext_vector_type(4)));
typedef short s16x8 __attribute__((ext_vector_type(8)));

__device__ __forceinline__ float bf2f(unsigned short u) {
  union { unsigned int i; float f; } c; c.i = ((unsigned int)u) << 16; return c.f;
}
__device__ __forceinline__ unsigned short f2bf(float f) {
  union { float f; unsigned int i; } c; c.f = f;
  unsigned int r = c.i + 0x7FFFu + ((c.i >> 16) & 1u);   // round-nearest-even
  return (unsigned short)(r >> 16);
}

// Async global->LDS, 16B per lane. LDS dest is wave-uniform base + lane*16.
__device__ __forceinline__ void gl_lds16(const unsigned short* g, unsigned short* l) {
  __builtin_amdgcn_global_load_lds(
      (const __attribute__((address_space(1))) unsigned int*)g,
      (__attribute__((address_space(3))) unsigned int*)l, 16, 0, 0);
}

// XCD-bijective row-major block swizzle (m204 formula; handles nwg%8 != 0).
// Returns seq in [0,nwg): XCD x owns a CONTIGUOUS run of row-major seq values
// so A row-panels + B stay L2-resident per XCD. Pure permutation.
__device__ __forceinline__ int xcd_seq() {
  const int nbx = gridDim.x;
  const int nwg = nbx * gridDim.y;
  const int orig = blockIdx.x + nbx * blockIdx.y;
  const int q = nwg >> 3, rr = nwg & 7;
  const int xcd = orig & 7, j = orig >> 3;
  return (xcd < rr ? xcd * (q + 1) : rr * (q + 1) + (xcd - rr) * q) + j;
}

// ---------------------------------------------------------------------------
__global__ __launch_bounds__(256) void cast_kernel(
    const float* __restrict__ s, unsigned short* __restrict__ d, int n4)
{
  int i = blockIdx.x * 256 + threadIdx.x;
  if (i < n4) {
    float4 v = *(const float4*)&s[(size_t)i*4];
    ushort4 o; o.x = f2bf(v.x); o.y = f2bf(v.y); o.z = f2bf(v.z); o.w = f2bf(v.w);
    *(ushort4*)&d[(size_t)i*4] = o;
  }
}

// ---------------------------------------------------------------------------
// V transpose: vtmp (bh, n, d) -> vt (bh, d, m=n) stride VTS.
// 64x64 LDS tile, coalesced 16B reads AND writes. Pad stride 66.
// ---------------------------------------------------------------------------
#define TVP 66
__global__ __launch_bounds__(256) void vtrans_kernel(
    const unsigned short* __restrict__ v, unsigned short* __restrict__ vt)
{
  __shared__ __align__(16) unsigned short T[64*TVP];
  const int tid = threadIdx.x;
  const int bh = blockIdx.y;
  const int n0 = blockIdx.x * 64;
  const s16x8 z8 = {0,0,0,0,0,0,0,0};
  {
    int r = tid >> 2, seg = tid & 3;
    int n = n0 + r;
    s16x8 a0 = z8, a1 = z8;
    if (n < SEQ) {
      const unsigned short* src = &v[((size_t)bh*SEQ + n)*DH + seg*16];
      a0 = *(const s16x8*)&src[0];
      a1 = *(const s16x8*)&src[8];
    }
    *(s16x8*)&T[r*TVP + seg*16]     = a0;
    *(s16x8*)&T[r*TVP + seg*16 + 8] = a1;
  }
  __syncthreads();
  {
    int d = tid >> 2, jseg = tid & 3;
    int jb = jseg * 16;
    unsigned short* dst = &vt[((size_t)bh*DH + d)*VTS + n0 + jb];
    if (n0 + jb + 15 < SEQ) {
      s16x8 b0, b1;
#pragma unroll
      for (int s = 0; s < 8; ++s) b0[s] = T[(jb + s)*TVP + d];
#pragma unroll
      for (int s = 0; s < 8; ++s) b1[s] = T[(jb + 8 + s)*TVP + d];
      *(s16x8*)&dst[0] = b0;
      *(s16x8*)&dst[8] = b1;
    } else {
      for (int s = 0; s < 16; ++s) {
        if (n0 + jb + s < SEQ) dst[s] = T[(jb + s)*TVP + d];
      }
    }
  }
}

// ---------------------------------------------------------------------------
// bf16 MFMA GEMM (NT), 128x128 tile, double-buffered LDS (T3 2-phase),
// + XCD row-major swizzle: staging latency IS exposed here (vmcnt drain at
// every K-step barrier), so L2-residency of A row-panels (~1MB/XCD) + B
// (3.5MB) shortens the drain. Bit-identical (pure block permutation).
// mode 0: scatter q/k/v coalesced (b,h,n,d). mode 1: fp32 row-major.
// ---------------------------------------------------------------------------
#define GT 128
__global__ __launch_bounds__(256) void gemm_bf16(
    const unsigned short* __restrict__ A, const unsigned short* __restrict__ Bm,
    unsigned short* __restrict__ Cq, unsigned short* __restrict__ Ck,
    unsigned short* __restrict__ Cv, float* __restrict__ Cf,
    int M, int N, int mode)
{
  __shared__ __align__(16) unsigned short AsF[2][GT*32];
  __shared__ __align__(16) unsigned short BsF[2][GT*32];
  const int tid = threadIdx.x;
  const int wave = tid >> 6;
  const int lane = tid & 63;
  const int wr = wave >> 1, wc = wave & 1;
  const int li = lane & 15, g = lane >> 4;
  const int seq = xcd_seq();
  const int nbx = gridDim.x;
  const int r0 = (seq / nbx) * GT, c0 = (seq % nbx) * GT;

  const int row1 = tid >> 2,          seg1 = tid & 3;
  const int row2 = (tid + 256) >> 2,  seg2 = tid & 3;
  const unsigned short* ga1 = &A [(size_t)(r0 + row1)*EMB + seg1*8];
  const unsigned short* ga2 = &A [(size_t)(r0 + row2)*EMB + seg2*8];
  const unsigned short* gb1 = &Bm[(size_t)(c0 + row1)*EMB + seg1*8];
  const unsigned short* gb2 = &Bm[(size_t)(c0 + row2)*EMB + seg2*8];

  f32x4 acc[4][4];
#pragma unroll
  for (int i = 0; i < 4; ++i)
#pragma unroll
    for (int j = 0; j < 4; ++j) { acc[i][j][0]=0.f; acc[i][j][1]=0.f; acc[i][j][2]=0.f; acc[i][j][3]=0.f; }

  // prologue: stage tile 0 into buffer 0
  gl_lds16(ga1, &AsF[0][wave*512]);
  gl_lds16(ga2, &AsF[0][2048 + wave*512]);
  gl_lds16(gb1, &BsF[0][wave*512]);
  gl_lds16(gb2, &BsF[0][2048 + wave*512]);

  int cur = 0;
  for (int k0 = 0; k0 < EMB; k0 += 32) {
    __syncthreads();   // drains gl_lds for buf[cur] (issued last iter, flew
                       // under last iter's compute); syncs buf reuse
    if (k0 + 32 < EMB) {
      int kn = k0 + 32;
      gl_lds16(ga1 + kn, &AsF[cur^1][wave*512]);
      gl_lds16(ga2 + kn, &AsF[cur^1][2048 + wave*512]);
      gl_lds16(gb1 + kn, &BsF[cur^1][wave*512]);
      gl_lds16(gb2 + kn, &BsF[cur^1][2048 + wave*512]);
    }

    s16x8 af[4], bfv[4];
#pragma unroll
    for (int i = 0; i < 4; ++i) af[i]  = *(const s16x8*)&AsF[cur][(wr*64 + i*16 + li)*32 + g*8];
#pragma unroll
    for (int j = 0; j < 4; ++j) bfv[j] = *(const s16x8*)&BsF[cur][(wc*64 + j*16 + li)*32 + g*8];
#pragma unroll
    for (int i = 0; i < 4; ++i)
#pragma unroll
      for (int j = 0; j < 4; ++j)
        acc[i][j] = __builtin_amdgcn_mfma_f32_16x16x32_bf16(af[i], bfv[j], acc[i][j], 0, 0, 0);
    cur ^= 1;
  }

  if (mode == 1) {
#pragma unroll
    for (int i = 0; i < 4; ++i) {
      int rbase = r0 + wr*64 + i*16 + g*4;
#pragma unroll
      for (int rg = 0; rg < 4; ++rg) {
        int gr = rbase + rg;
        if (gr >= M) continue;
        float* crow = &Cf[(size_t)gr*N + c0 + wc*64 + li];
#pragma unroll
        for (int j = 0; j < 4; ++j) crow[j*16] = acc[i][j][rg];
      }
    }
  } else {
    // per-j column decomposition; all targets share (b,h,n,d) addressing now
    unsigned short* cb[4]; size_t coff[4];
#pragma unroll
    for (int j = 0; j < 4; ++j) {
      int col = c0 + wc*64 + j*16 + li;
      int t  = col / EMB;
      int ct = col - t*EMB;
      int h  = ct >> 6, dd = ct & 63;
      cb[j]   = (t == 0) ? Cq : (t == 1) ? Ck : Cv;
      coff[j] = (size_t)h*SEQ*DH + dd;
    }
#pragma unroll
    for (int i = 0; i < 4; ++i) {
      int rbase = r0 + wr*64 + i*16 + g*4;
#pragma unroll
      for (int rg = 0; rg < 4; ++rg) {
        int gr = rbase + rg;
        if (gr >= M) continue;
        int brow = gr / SEQ, nrow = gr - brow*SEQ;
        size_t roff = ((size_t)brow*NH)*SEQ*DH + (size_t)nrow*DH;
#pragma unroll
        for (int j = 0; j < 4; ++j)
          cb[j][roff + coff[j]] = f2bf(acc[i][j][rg]);
      }
    }
  }
}

// ---------------------------------------------------------------------------
// Proj GEMM: 64x128 tile, fp32 output (round-9 proven, merged both chunks)
// + XCD row-major swizzle (A ~1.7MB + B 1.2MB resident per XCD).
// ---------------------------------------------------------------------------
__global__ __launch_bounds__(256) void gemm64_kernel(
    const unsigned short* __restrict__ A, const unsigned short* __restrict__ Bm,
    float* __restrict__ Cf, int M, int N)
{
  __shared__ __align__(16) unsigned short As[2][64*32];
  __shared__ __align__(16) unsigned short Bs[2][128*32];
  const int tid = threadIdx.x;
  const int wave = tid >> 6;
  const int lane = tid & 63;
  const int li = lane & 15, g = lane >> 4;
  const int seq = xcd_seq();
  const int nbx = gridDim.x;
  const int r0 = (seq / nbx) * 64, c0 = (seq % nbx) * GT;

  const int rowA = tid >> 2, seg = tid & 3;          // 256 chunks of A
  const int rowB2 = (tid + 256) >> 2;                // B rows 64..127
  const unsigned short* ga  = &A [(size_t)(r0 + rowA)*EMB + seg*8];
  const unsigned short* gb1 = &Bm[(size_t)(c0 + rowA)*EMB + seg*8];
  const unsigned short* gb2 = &Bm[(size_t)(c0 + rowB2)*EMB + seg*8];

  f32x4 acc[4][2];
#pragma unroll
  for (int i = 0; i < 4; ++i)
#pragma unroll
    for (int j = 0; j < 2; ++j) { acc[i][j][0]=0.f; acc[i][j][1]=0.f; acc[i][j][2]=0.f; acc[i][j][3]=0.f; }

  gl_lds16(ga,  &As[0][wave*512]);
  gl_lds16(gb1, &Bs[0][wave*512]);
  gl_lds16(gb2, &Bs[0][2048 + wave*512]);

  int cur = 0;
  for (int k0 = 0; k0 < EMB; k0 += 32) {
    __syncthreads();
    if (k0 + 32 < EMB) {
      int kn = k0 + 32;
      gl_lds16(ga + kn,  &As[cur^1][wave*512]);
      gl_lds16(gb1 + kn, &Bs[cur^1][wave*512]);
      gl_lds16(gb2 + kn, &Bs[cur^1][2048 + wave*512]);
    }

    s16x8 af[4], bfv[2];
#pragma unroll
    for (int i = 0; i < 4; ++i) af[i]  = *(const s16x8*)&As[cur][(i*16 + li)*32 + g*8];
#pragma unroll
    for (int j = 0; j < 2; ++j) bfv[j] = *(const s16x8*)&Bs[cur][(wave*32 + j*16 + li)*32 + g*8];
#pragma unroll
    for (int i = 0; i < 4; ++i)
#pragma unroll
      for (int j = 0; j < 2; ++j)
        acc[i][j] = __builtin_amdgcn_mfma_f32_16x16x32_bf16(af[i], bfv[j], acc[i][j], 0, 0, 0);
    cur ^= 1;
  }

#pragma unroll
  for (int i = 0; i < 4; ++i) {
    int rbase = r0 + i*16 + g*4;
#pragma unroll
    for (int rg = 0; rg < 4; ++rg) {
      int gr = rbase + rg;
      if (gr >= M) continue;
      float* crow = &Cf[(size_t)gr*N + c0 + wave*32 + li];
#pragma unroll
      for (int j = 0; j < 2; ++j) crow[j*16] = acc[i][j][rg];
    }
  }
}

// ---------------------------------------------------------------------------
// MFMA fused attention — round-11 kernel VERBATIM (81us, XCD swizzle,
// NO-MAX softmax). VGPR=60 must stay under the 64-VGPR occupancy cliff.
// LDS: Ps 18688 + TBCS 3392 + red 256 + VXL/VYL 6400 = 28736.
// ---------------------------------------------------------------------------
#define TRB 16
#define SW 584

#define FOR_KT(X) X(0) X(1) X(2) X(3) X(4) X(5) X(6) X(7) X(8) X(9)

__global__ __launch_bounds__(256) void attn_kernel(
    const unsigned short* __restrict__ qg, const unsigned short* __restrict__ kg,
    const unsigned short* __restrict__ vtg,
    const float* __restrict__ qxe, const float* __restrict__ qye,
    const float* __restrict__ vxe, const float* __restrict__ vye,
    unsigned short* __restrict__ og)
{
  __shared__ __align__(16) unsigned short Ps[TRB][SW];
  __shared__ __align__(16) unsigned char  TBCS[3392];
  __shared__ __align__(16) float red[TRB][4];
  __shared__ __align__(16) unsigned short VXL[50*32];
  __shared__ __align__(16) unsigned short VYL[50*32];

  const int tid  = threadIdx.x;
  const int wave = tid >> 6, lane = tid & 63;
  const int li = lane & 15, gg = lane >> 4;
  // ---- XCD-aware swizzle (pure permutation of (bx, bh); 3552 = 8*444) ----
  const int raw = blockIdx.x + 37 * blockIdx.y;
  const int xcd = raw & 7;
  const int jj  = raw >> 3;            // 0..443
  const int bh  = xcd + 8 * (jj / 37); // XCD x serves bhs == x mod 8
  const int r0  = (jj % 37) * TRB;
  const size_t qkbase = (size_t)bh * SEQ * DH;
  const size_t vtbase = (size_t)bh * DH * VTS;
  const s16x8 z8 = {0,0,0,0,0,0,0,0};

  // ---- stage v-bias tables into LDS as bf16 (1600 entries each) ----
  for (int t4 = tid; t4 < 400; t4 += 256) {
    float4 a = ((const float4*)vxe)[t4];
    float4 b = ((const float4*)vye)[t4];
    ushort4 oa; oa.x=f2bf(a.x); oa.y=f2bf(a.y); oa.z=f2bf(a.z); oa.w=f2bf(a.w);
    ushort4 ob; ob.x=f2bf(b.x); ob.y=f2bf(b.y); ob.z=f2bf(b.z); ob.w=f2bf(b.w);
    ((ushort4*)VXL)[t4] = oa;
    ((ushort4*)VYL)[t4] = ob;
  }

  // ---- Q A-frags from global (kept resident through phase A) ----
  s16x8 qf0, qf1;
  {
    int n = r0 + li;
    qf0 = (n < SEQ) ? *(const s16x8*)&qg[qkbase + (size_t)n*DH + gg*8] : z8;
    qf1 = (n < SEQ) ? *(const s16x8*)&qg[qkbase + (size_t)n*DH + 32 + gg*8] : z8;
  }

  // ---- early K step-0 prefetch (lands during TB build / barrier 1) ----
  const unsigned short* kwv = &kg[qkbase + (size_t)(wave*16 + li)*DH];
  s16x8 kp0 = *(const s16x8*)&kwv[gg*8];
  s16x8 kp1 = *(const s16x8*)&kwv[32 + gg*8];

  // ---- bias dot tables via MFMA: qx_dot/qy_dot [16 rows][50 bins] bf16,
  //      row stride 104, y half at +52 (bank de-alias) ----
  unsigned short* TB = (unsigned short*)TBCS;
  {
    int bin = wave*16 + li;
    s16x8 bx = z8, by = z8;
    if (bin < 50) {
      float4 x0 = *(const float4*)&qxe[bin*32 + gg*8];
      float4 x1 = *(const float4*)&qxe[bin*32 + gg*8 + 4];
      float4 y0 = *(const float4*)&qye[bin*32 + gg*8];
      float4 y1 = *(const float4*)&qye[bin*32 + gg*8 + 4];
      bx[0]=f2bf(x0.x); bx[1]=f2bf(x0.y); bx[2]=f2bf(x0.z); bx[3]=f2bf(x0.w);
      bx[4]=f2bf(x1.x); bx[5]=f2bf(x1.y); bx[6]=f2bf(x1.z); bx[7]=f2bf(x1.w);
      by[0]=f2bf(y0.x); by[1]=f2bf(y0.y); by[2]=f2bf(y0.z); by[3]=f2bf(y0.w);
      by[4]=f2bf(y1.x); by[5]=f2bf(y1.y); by[6]=f2bf(y1.z); by[7]=f2bf(y1.w);
    }
    f32x4 ax0={0.f,0.f,0.f,0.f}, ay0={0.f,0.f,0.f,0.f};
    ax0 = __builtin_amdgcn_mfma_f32_16x16x32_bf16(qf0, bx, ax0, 0,0,0);
    ay0 = __builtin_amdgcn_mfma_f32_16x16x32_bf16(qf1, by, ay0, 0,0,0);
    if (bin < 50) {
#pragma unroll
      for (int rg = 0; rg < 4; ++rg) {
        TB[(gg*4+rg)*104      + bin] = f2bf(ax0[rg]);
        TB[(gg*4+rg)*104 + 52 + bin] = f2bf(ay0[rg]);
      }
    }
  }

  // row coords for bias (per rg)
  int xn[4], yn[4];
#pragma unroll
  for (int rg = 0; rg < 4; ++rg) {
    int n = r0 + gg*4 + rg;
    if (n > 0 && n <= SEQ) { xn[rg] = (n-1) % 24; yn[rg] = (n-1) / 24; }
    else { xn[rg] = 0; yn[rg] = 0; }
  }
  __syncthreads();   // barrier 1: TB + VXL/VYL visible

  // ---- Phase A+B merged: QK^T + bias -> exp -> Ps + Lp; K pipelined ----
  f32x4 LpA = {0.f,0.f,0.f,0.f};

#define KTSTEP(KT) do {                                                       \
    const int m0_ = (KT)*64;                                                  \
    s16x8 kc0_ = kp0, kc1_ = kp1;                                             \
    if ((KT) < 9) {                                                           \
      kp0 = *(const s16x8*)&kwv[(size_t)(m0_ + 64)*DH + gg*8];                \
      kp1 = *(const s16x8*)&kwv[(size_t)(m0_ + 64)*DH + 32 + gg*8];           \
    }                                                                         \
    f32x4 a0_ = {0.f,0.f,0.f,0.f};                                            \
    a0_ = __builtin_amdgcn_mfma_f32_16x16x32_bf16(qf0, kc0_, a0_, 0,0,0);     \
    a0_ = __builtin_amdgcn_mfma_f32_16x16x32_bf16(qf1, kc1_, a0_, 0,0,0);     \
    int m_ = m0_ + wave*16 + li;                                              \
    int xm_ = 0, ym_ = 0;                                                     \
    bool mv_ = (m_ > 0 && m_ < SEQ);                                          \
    if (mv_) { xm_ = (m_-1) % 24; ym_ = (m_-1) / 24; }                        \
    _Pragma("unroll")                                                         \
    for (int rg = 0; rg < 4; ++rg) {                                          \
      int nloc_ = gg*4 + rg; int n_ = r0 + nloc_;                             \
      float s_ = a0_[rg]; int xi_ = 0, yi_ = 0;                               \
      if (mv_ && n_ > 0) { xi_ = xm_ - xn[rg] + 25; yi_ = ym_ - yn[rg] + 25; }\
      s_ = (s_ + bf2f(TB[nloc_*104 + xi_]) + bf2f(TB[nloc_*104 + 52 + yi_])) * 0.125f; \
      float p_ = (m_ < SEQ) ? __expf(s_) : 0.f;                               \
      LpA[rg] += p_;                                                          \
      if (m_ < SW) Ps[nloc_][m_] = f2bf(p_);                                  \
    }                                                                         \
  } while (0);
  FOR_KT(KTSTEP)
#undef KTSTEP

  // ---- early V step-0 prefetch (rides through CS phase) ----
  const unsigned short* vwv = &vtg[vtbase + (size_t)(wave*16 + li)*VTS];
  s16x8 vp0 = *(const s16x8*)&vwv[gg*8];
  s16x8 vp1 = *(const s16x8*)&vwv[32 + gg*8];

  // ---- row-sum reduce ----
#pragma unroll
  for (int rg = 0; rg < 4; ++rg) {
    float s = LpA[rg];
    s += __shfl_xor(s, 1); s += __shfl_xor(s, 2);
    s += __shfl_xor(s, 4); s += __shfl_xor(s, 8);
    if (li == 0) red[gg*4 + rg][wave] = s;
  }
  __syncthreads();   // barrier 2: Ps complete; red sums ready; TB dead
  float* CS = (float*)TBCS;                            // [16][49]
  if (wave == 0 && li == 0) {
#pragma unroll
    for (int rg = 0; rg < 4; ++rg) {
      int nloc = gg*4 + rg;
      float4 r4 = *(float4*)&red[nloc][0];
      CS[nloc*49 + 48] = r4.x + r4.y + r4.z + r4.w;
    }
  }
  {
    int r = tid >> 4, kb = tid & 15;        // div-free: 16 threads per row
#pragma unroll
    for (int kk = 0; kk < 3; ++kk) {
      int k = kb + kk*16;
      float s = 0.f;
      if (k < 24) {
#pragma unroll
        for (int c2 = 0; c2 < 24; ++c2) s += bf2f(Ps[r][1 + c2*24 + k]);
      } else {
        int rw = k - 24;
#pragma unroll
        for (int c2 = 0; c2 < 24; ++c2) s += bf2f(Ps[r][1 + rw*24 + c2]);
      }
      CS[r*49 + k] = s;
    }
  }
  __syncthreads();   // barrier 3: CS complete (epilogue reads it)

  // ---- Phase C: O = P.V via MFMA, V + Ps pipelined; NO barriers ----
  f32x4 oa0 = {0.f,0.f,0.f,0.f};
  s16x8 ap0 = *(const s16x8*)&Ps[li][gg*8];
  s16x8 ap1 = *(const s16x8*)&Ps[li][32 + gg*8];
#pragma unroll
  for (int vt = 0; vt < 10; ++vt) {
    s16x8 vc0 = vp0, vc1 = vp1;
    s16x8 ac0 = ap0, ac1 = ap1;
    if (vt < 9) {
      int mn = (vt + 1)*64;
      vp0 = *(const s16x8*)&vwv[mn + gg*8];
      vp1 = *(const s16x8*)&vwv[mn + 32 + gg*8];
      if (vt < 8) {
        ap0 = *(const s16x8*)&Ps[li][mn + gg*8];
        ap1 = *(const s16x8*)&Ps[li][mn + 32 + gg*8];
      } else {
        ap0 = (gg == 0) ? *(const s16x8*)&Ps[li][576] : z8;   // probs 577..583 = 0
        ap1 = z8;
      }
    }
    oa0 = __builtin_amdgcn_mfma_f32_16x16x32_bf16(ac0, vc0, oa0, 0,0,0);
    oa0 = __builtin_amdgcn_mfma_f32_16x16x32_bf16(ac1, vc1, oa0, 0,0,0);
  }

  // ---- Epilogue: + v-bias (bf16 LDS tables), /L, write bf16 (B,N,H,D) ----
  {
    int d = wave*16 + li;
    const unsigned short* tabL = (d < 32) ? VXL : VYL;
    int dd = d & 31;
    bool useX = (d < 32);
    int bI = bh / NH, hI = bh - bI*NH;
#pragma unroll
    for (int rg = 0; rg < 4; ++rg) {
      int nloc = gg*4 + rg;
      int n = r0 + nloc;
      if (n >= SEQ) continue;
      float Lr = CS[nloc*49 + 48];
      float bias;
      if (n == 0) {
        bias = Lr * bf2f(tabL[dd]);
      } else {
        int cn = useX ? ((n-1) % 24) : ((n-1) / 24);
        const unsigned short* trow = &tabL[(25 - cn)*32 + dd];
        const float* csrow = &CS[nloc*49 + (useX ? 0 : 24)];
        float b0 = bf2f(Ps[nloc][0]) * bf2f(tabL[dd]);
        float b1 = 0.f, b2 = 0.f, b3 = 0.f;
#pragma unroll
        for (int c = 0; c < 24; c += 4) {
          b0 = fmaf(csrow[c    ], bf2f(trow[(c    )*32]), b0);
          b1 = fmaf(csrow[c + 1], bf2f(trow[(c + 1)*32]), b1);
          b2 = fmaf(csrow[c + 2], bf2f(trow[(c + 2)*32]), b2);
          b3 = fmaf(csrow[c + 3], bf2f(trow[(c + 3)*32]), b3);
        }
        bias = (b0 + b1) + (b2 + b3);
      }
      float o = (oa0[rg] + bias) / Lr;
      og[(((size_t)bI*SEQ + n)*NH + hI)*DH + d] = f2bf(o);
    }
  }
}

// ---------------------------------------------------------------------------
// ws (ushorts): q 3.545M, k 3.545M, vt 3.637M, ows 7.090M (BOTH chunks),
// xbf 3.545M, wqkv 1.769M, wproj 0.590M, vtmp 3.545M => 54.5 MB (< 56.7).
// ---------------------------------------------------------------------------
extern "C" void kernel_launch(void* const* d_in, const int* in_sizes, int n_in,
                              void* d_out, int out_size, void* d_ws, size_t ws_size,
                              hipStream_t stream)
{
  const float* x     = (const float*)d_in[0];
  const float* qkvw  = (const float*)d_in[1];
  const float* projw = (const float*)d_in[2];
  const float* qxe   = (const float*)d_in[3];
  const float* qye   = (const float*)d_in[4];
  const float* vxe   = (const float*)d_in[5];
  const float* vye   = (const float*)d_in[6];
  float* out = (float*)d_out;

  const size_t SLc = (size_t)BHC * SEQ * DH;        // 3,545,088
  const size_t VTL = (size_t)BHC * DH * VTS;        // 3,637,248
  unsigned short* qws   = (unsigned short*)d_ws;
  unsigned short* kws   = qws + SLc;
  unsigned short* vtws  = kws + SLc;
  unsigned short* ows   = vtws + VTL;               // 2*SLc (both chunks)
  unsigned short* xbf   = ows + 2*SLc;
  unsigned short* wqkv  = xbf + SLc;
  unsigned short* wproj = wqkv + (size_t)3*EMB*EMB;
  unsigned short* vtmp  = wproj + (size_t)EMB*EMB;

  cast_kernel<<<(3*EMB*EMB/4 + 255)/256, 256, 0, stream>>>(qkvw, wqkv, 3*EMB*EMB/4);
  cast_kernel<<<(EMB*EMB/4 + 255)/256, 256, 0, stream>>>(projw, wproj, EMB*EMB/4);

  dim3 g1(3*EMB/GT, (MC + GT - 1)/GT);   // 18 x 37: qkv GEMM (128^2, proven)
  dim3 gt(10, BHC);                      // V transpose: 10 n-tiles x 96 bh
  dim3 g2((SEQ + TRB - 1)/TRB, BHC);     // 37 x 96
  dim3 g3(EMB/GT, (2*MC + 63)/64);       // 6 x 145: merged proj GEMM

  for (int c = 0; c < NC; ++c) {
    const float* xc = x + (size_t)c * MC * EMB;
    cast_kernel<<<(MC*EMB/4 + 255)/256, 256, 0, stream>>>(xc, xbf, MC*EMB/4);
    gemm_bf16<<<g1, 256, 0, stream>>>(xbf, wqkv, qws, kws, vtmp, nullptr, MC, 3*EMB, 0);
    vtrans_kernel<<<gt, 256, 0, stream>>>(vtmp, vtws);
    attn_kernel<<<g2, 256, 0, stream>>>(qws, kws, vtws, qxe, qye, vxe, vye,
                                        ows + (size_t)c * SLc);
  }
  // one merged proj GEMM over both chunks (depends only on attn outputs)
  gemm64_kernel<<<g3, 256, 0, stream>>>(ows, wproj, out, 2*MC, EMB);
}